// Round 11
// baseline (924.441 us; speedup 1.0000x reference)
//
#include <hip/hip_runtime.h>
#include <math.h>

#define NN 50000
#define EE 600000
#define IND 128
#define HIDD 64
#define NH 4
#define EDD 16
#define OUTD 2
#define C1 256  /* NH*HID */

__device__ __forceinline__ float lrelu(float v){ return v > 0.f ? v : 0.2f*v; }
// bf16 pack (round-to-nearest-even) / unpack
__device__ __forceinline__ unsigned short f2bf(float f){
    unsigned b = __float_as_uint(f);
    b += 0x7FFF + ((b >> 16) & 1);
    return (unsigned short)(b >> 16);
}
__device__ __forceinline__ float bf2f(unsigned short h){
    return __uint_as_float(((unsigned)h) << 16);
}

// ---------------- CSR build: histogram ---------------------------------------
__global__ __launch_bounds__(256) void k_hist(const int* __restrict__ dst, int* __restrict__ cnt)
{
    int stride = gridDim.x * blockDim.x;
    for (int e = blockIdx.x * blockDim.x + threadIdx.x; e < EE; e += stride)
        atomicAdd(&cnt[dst[e]], 1);
}

// ---------------- CSR build: exclusive scan (single block, 1024 thr) ---------
__global__ __launch_bounds__(1024) void k_scan(const int* __restrict__ cnt, int* __restrict__ rs)
{
    __shared__ int wsum[16];
    __shared__ int wpref[16];
    int t = threadIdx.x, lane = t & 63, w = t >> 6;
    int running = 0;
    for (int base = 0; base < NN; base += 1024) {
        int idx = base + t;
        int v = (idx < NN) ? cnt[idx] : 0;
        int sc = v;
#pragma unroll
        for (int off = 1; off < 64; off <<= 1) {
            int u = __shfl_up(sc, off, 64);
            if (lane >= off) sc += u;
        }
        if (lane == 63) wsum[w] = sc;
        __syncthreads();
        if (w == 0 && lane < 16) {
            int x = wsum[lane];
#pragma unroll
            for (int off = 1; off < 16; off <<= 1) {
                int u = __shfl_up(x, off, 64);
                if (lane >= off) x += u;
            }
            wpref[lane] = x;
        }
        __syncthreads();
        int woff = (w == 0) ? 0 : wpref[w - 1];
        if (idx < NN) rs[idx] = running + woff + sc - v;
        running += wpref[15];
        __syncthreads();
    }
    if (t == 0) rs[NN] = running;
}

// ---------------- CSR build: scatter src ids + edge attrs in CSR order -------
__global__ __launch_bounds__(256) void k_scatter(
    const int* __restrict__ src, const int* __restrict__ dst,
    const float* __restrict__ ea,
    const int* __restrict__ rs, int* __restrict__ cur,
    int* __restrict__ esrc, float* __restrict__ ea_s)
{
    int stride = gridDim.x * blockDim.x;
    for (int e = blockIdx.x * blockDim.x + threadIdx.x; e < EE; e += stride) {
        int d = dst[e];
        int p = rs[d] + atomicAdd(&cur[d], 1);
        esrc[p] = src[e];
        const float4* s4 = (const float4*)(ea + (size_t)e * EDD);
        float4* d4 = (float4*)(ea_s + (size_t)p * EDD);
        d4[0] = s4[0]; d4[1] = s4[1]; d4[2] = s4[2]; d4[3] = s4[3];
    }
}

// ---------------- layer 1 node linear: xl1(bf16) = x@W1l+b1l, xr1 = x@W1r+b1r
__global__ __launch_bounds__(256) void k_lin1(
    const float* __restrict__ x, const float* __restrict__ Wl, const float* __restrict__ bl,
    const float* __restrict__ Wr, const float* __restrict__ br,
    unsigned short* __restrict__ xl, float* __restrict__ xr)
{
    __shared__ float As[16 * IND];
    int t = threadIdx.x;
    int row0 = blockIdx.x * 16;
#pragma unroll
    for (int j = 0; j < 8; ++j) {
        int idx = t + j * 256;
        int r = idx >> 7, c = idx & 127;
        As[idx] = (row0 + r < NN) ? x[(size_t)(row0 + r) * IND + c] : 0.f;
    }
    __syncthreads();
    float accl[16], accr[16];
    float bL = bl[t], bR = br[t];
#pragma unroll
    for (int i = 0; i < 16; ++i) { accl[i] = bL; accr[i] = bR; }
    for (int k = 0; k < IND; k += 4) {
        float wl0 = Wl[(k+0) * C1 + t], wl1 = Wl[(k+1) * C1 + t];
        float wl2 = Wl[(k+2) * C1 + t], wl3 = Wl[(k+3) * C1 + t];
        float wr0 = Wr[(k+0) * C1 + t], wr1 = Wr[(k+1) * C1 + t];
        float wr2 = Wr[(k+2) * C1 + t], wr3 = Wr[(k+3) * C1 + t];
#pragma unroll
        for (int i = 0; i < 16; ++i) {
            float4 a = *((const float4*)&As[i * IND + k]);
            accl[i] = fmaf(a.x, wl0, accl[i]); accl[i] = fmaf(a.y, wl1, accl[i]);
            accl[i] = fmaf(a.z, wl2, accl[i]); accl[i] = fmaf(a.w, wl3, accl[i]);
            accr[i] = fmaf(a.x, wr0, accr[i]); accr[i] = fmaf(a.y, wr1, accr[i]);
            accr[i] = fmaf(a.z, wr2, accr[i]); accr[i] = fmaf(a.w, wr3, accr[i]);
        }
    }
#pragma unroll
    for (int i = 0; i < 16; ++i) {
        int r = row0 + i;
        if (r < NN) {
            xl[(size_t)r * C1 + t] = f2bf(accl[i]);
            xr[(size_t)r * C1 + t] = accr[i];
        }
    }
}

// one online-softmax edge step for layer 1 (uses outer-scope Wreg/sb4/sa4/xr4/m/den/acc)
#define GAT1_EDGE(XU, A0, A1, A2, A3) {                                        \
    float4 xl4 = make_float4(bf2f((XU).x), bf2f((XU).y), bf2f((XU).z), bf2f((XU).w)); \
    float ev[16] = {(A0).x,(A0).y,(A0).z,(A0).w,(A1).x,(A1).y,(A1).z,(A1).w,   \
                    (A2).x,(A2).y,(A2).z,(A2).w,(A3).x,(A3).y,(A3).z,(A3).w};  \
    float4 xe = sb4;                                                           \
    _Pragma("unroll")                                                          \
    for (int k = 0; k < 16; ++k) {                                             \
        xe.x = fmaf(ev[k], Wreg[k].x, xe.x);                                   \
        xe.y = fmaf(ev[k], Wreg[k].y, xe.y);                                   \
        xe.z = fmaf(ev[k], Wreg[k].z, xe.z);                                   \
        xe.w = fmaf(ev[k], Wreg[k].w, xe.w);                                   \
    }                                                                          \
    float vx = lrelu(xl4.x + xr4.x + xe.x);                                    \
    float vy = lrelu(xl4.y + xr4.y + xe.y);                                    \
    float vz = lrelu(xl4.z + xr4.z + xe.z);                                    \
    float vw = lrelu(xl4.w + xr4.w + xe.w);                                    \
    float p = vx * sa4.x + vy * sa4.y + vz * sa4.z + vw * sa4.w;               \
    p += __shfl_xor(p, 1, 64);                                                 \
    p += __shfl_xor(p, 2, 64);                                                 \
    p += __shfl_xor(p, 4, 64);                                                 \
    p += __shfl_xor(p, 8, 64);                                                 \
    float mn = fmaxf(m, p);                                                    \
    float scl = __expf(m - mn);                                                \
    float el  = __expf(p - mn);                                                \
    den = fmaf(den, scl, el);                                                  \
    acc.x = fmaf(acc.x, scl, el * xl4.x);                                      \
    acc.y = fmaf(acc.y, scl, el * xl4.y);                                      \
    acc.z = fmaf(acc.z, scl, el * xl4.z);                                      \
    acc.w = fmaf(acc.w, scl, el * xl4.w);                                      \
    m = mn;                                                                    \
}

// ---------------- layer 1 fused GAT: wave/node, 4-way unroll -----------------
// 4 independent xl gathers issued before the compute phase: 2x the in-flight
// MLP of R9's 2-way (grid shape was proven ~neutral in R10; per-wave MLP is
// the remaining lever at constant bytes).
__global__ __launch_bounds__(256, 3) void k_gat1(
    const int* __restrict__ rs, const int* __restrict__ esrc,
    const float* __restrict__ ea_s, const float* __restrict__ We, const float* __restrict__ be,
    const float* __restrict__ att, const unsigned short* __restrict__ xl,
    const float* __restrict__ xr, float* __restrict__ h1)
{
    int t = threadIdx.x, lane = t & 63, w = t >> 6;
    int c4 = lane * 4;                 // lane owns 4 contiguous channels, head = lane>>4
    float4 Wreg[16];
#pragma unroll
    for (int k = 0; k < 16; ++k) Wreg[k] = *((const float4*)(We + k * C1 + c4));
    float4 sb4 = *((const float4*)(be + c4));
    float4 sa4 = *((const float4*)(att + c4));
    for (int n = blockIdx.x * 4 + w; n < NN; n += gridDim.x * 4) {
        int beg = rs[n], end = rs[n + 1];
        float4 xr4 = *((const float4*)(xr + (size_t)n * C1 + c4));
        float m = -INFINITY, den = 0.f;
        float4 acc = make_float4(0.f, 0.f, 0.f, 0.f);
        int i = beg;
        for (; i + 4 <= end; i += 4) {
            int s0 = esrc[i], s1 = esrc[i + 1], s2 = esrc[i + 2], s3 = esrc[i + 3];
            ushort4 xu0 = *((const ushort4*)(xl + (size_t)s0 * C1 + c4));
            ushort4 xu1 = *((const ushort4*)(xl + (size_t)s1 * C1 + c4));
            ushort4 xu2 = *((const ushort4*)(xl + (size_t)s2 * C1 + c4));
            ushort4 xu3 = *((const ushort4*)(xl + (size_t)s3 * C1 + c4));
            const float* ep = ea_s + (size_t)i * EDD;
            float4 a00 = *((const float4*)(ep +  0));
            float4 a01 = *((const float4*)(ep +  4));
            float4 a02 = *((const float4*)(ep +  8));
            float4 a03 = *((const float4*)(ep + 12));
            float4 a10 = *((const float4*)(ep + 16));
            float4 a11 = *((const float4*)(ep + 20));
            float4 a12 = *((const float4*)(ep + 24));
            float4 a13 = *((const float4*)(ep + 28));
            float4 a20 = *((const float4*)(ep + 32));
            float4 a21 = *((const float4*)(ep + 36));
            float4 a22 = *((const float4*)(ep + 40));
            float4 a23 = *((const float4*)(ep + 44));
            float4 a30 = *((const float4*)(ep + 48));
            float4 a31 = *((const float4*)(ep + 52));
            float4 a32 = *((const float4*)(ep + 56));
            float4 a33 = *((const float4*)(ep + 60));
            GAT1_EDGE(xu0, a00, a01, a02, a03);
            GAT1_EDGE(xu1, a10, a11, a12, a13);
            GAT1_EDGE(xu2, a20, a21, a22, a23);
            GAT1_EDGE(xu3, a30, a31, a32, a33);
        }
        for (; i + 2 <= end; i += 2) {
            int s0 = esrc[i], s1 = esrc[i + 1];
            ushort4 xu0 = *((const ushort4*)(xl + (size_t)s0 * C1 + c4));
            ushort4 xu1 = *((const ushort4*)(xl + (size_t)s1 * C1 + c4));
            const float* ep = ea_s + (size_t)i * EDD;
            float4 a00 = *((const float4*)(ep +  0));
            float4 a01 = *((const float4*)(ep +  4));
            float4 a02 = *((const float4*)(ep +  8));
            float4 a03 = *((const float4*)(ep + 12));
            float4 a10 = *((const float4*)(ep + 16));
            float4 a11 = *((const float4*)(ep + 20));
            float4 a12 = *((const float4*)(ep + 24));
            float4 a13 = *((const float4*)(ep + 28));
            GAT1_EDGE(xu0, a00, a01, a02, a03);
            GAT1_EDGE(xu1, a10, a11, a12, a13);
        }
        if (i < end) {
            int s0 = esrc[i];
            ushort4 xu0 = *((const ushort4*)(xl + (size_t)s0 * C1 + c4));
            const float* ep = ea_s + (size_t)i * EDD;
            float4 a00 = *((const float4*)(ep +  0));
            float4 a01 = *((const float4*)(ep +  4));
            float4 a02 = *((const float4*)(ep +  8));
            float4 a03 = *((const float4*)(ep + 12));
            GAT1_EDGE(xu0, a00, a01, a02, a03);
        }
        float r = den > 0.f ? 1.f / den : 0.f;
        float4 o = make_float4(acc.x * r, acc.y * r, acc.z * r, acc.w * r);
        *((float4*)(h1 + (size_t)n * C1 + c4)) = o;
    }
}

// ---------------- layer 2 node linear (fuses bias1+relu on load) -------------
__global__ __launch_bounds__(256) void k_lin2(
    const float* __restrict__ h1acc, const float* __restrict__ bias1,
    const float* __restrict__ Wl, const float* __restrict__ bl,
    const float* __restrict__ Wr, const float* __restrict__ br,
    unsigned short* __restrict__ xl2, float* __restrict__ xr2)
{
    __shared__ float As[16 * 260];
    int t = threadIdx.x;
    int row0 = blockIdx.x * 16;
    float b1 = bias1[t];
#pragma unroll
    for (int j = 0; j < 16; ++j) {
        float v = (row0 + j < NN) ? h1acc[(size_t)(row0 + j) * C1 + t] : 0.f;
        v = v + b1;
        As[j * 260 + t] = v > 0.f ? v : 0.f;
    }
    __syncthreads();
    int col = t & 63, g = t >> 6;
    float accl[4], accr[4];
    float bL = bl[col], bR = br[col];
#pragma unroll
    for (int i = 0; i < 4; ++i) { accl[i] = bL; accr[i] = bR; }
    for (int k = 0; k < C1; k += 4) {
        float wl0 = Wl[(k+0) * HIDD + col], wl1 = Wl[(k+1) * HIDD + col];
        float wl2 = Wl[(k+2) * HIDD + col], wl3 = Wl[(k+3) * HIDD + col];
        float wr0 = Wr[(k+0) * HIDD + col], wr1 = Wr[(k+1) * HIDD + col];
        float wr2 = Wr[(k+2) * HIDD + col], wr3 = Wr[(k+3) * HIDD + col];
#pragma unroll
        for (int i = 0; i < 4; ++i) {
            float4 a = *((const float4*)&As[(g * 4 + i) * 260 + k]);
            accl[i] = fmaf(a.x, wl0, accl[i]); accl[i] = fmaf(a.y, wl1, accl[i]);
            accl[i] = fmaf(a.z, wl2, accl[i]); accl[i] = fmaf(a.w, wl3, accl[i]);
            accr[i] = fmaf(a.x, wr0, accr[i]); accr[i] = fmaf(a.y, wr1, accr[i]);
            accr[i] = fmaf(a.z, wr2, accr[i]); accr[i] = fmaf(a.w, wr3, accr[i]);
        }
    }
#pragma unroll
    for (int i = 0; i < 4; ++i) {
        int r = row0 + g * 4 + i;
        if (r < NN) {
            xl2[(size_t)r * HIDD + col] = f2bf(accl[i]);
            xr2[(size_t)r * HIDD + col] = accr[i];
        }
    }
}

// one online-softmax edge step for layer 2
#define GAT2_EDGE(XU, A0, A1, A2, A3) {                                        \
    float xlv = bf2f(XU);                                                      \
    float ev[16] = {(A0).x,(A0).y,(A0).z,(A0).w,(A1).x,(A1).y,(A1).z,(A1).w,   \
                    (A2).x,(A2).y,(A2).z,(A2).w,(A3).x,(A3).y,(A3).z,(A3).w};  \
    float xe = bev;                                                            \
    _Pragma("unroll")                                                          \
    for (int k = 0; k < 16; ++k) xe = fmaf(ev[k], Wreg[k], xe);                \
    float v = lrelu(xlv + xrv + xe);                                           \
    float p = v * sav;                                                         \
    p += __shfl_xor(p, 1, 64);                                                 \
    p += __shfl_xor(p, 2, 64);                                                 \
    p += __shfl_xor(p, 4, 64);                                                 \
    p += __shfl_xor(p, 8, 64);                                                 \
    p += __shfl_xor(p, 16, 64);                                                \
    p += __shfl_xor(p, 32, 64);                                                \
    float mn = fmaxf(m, p);                                                    \
    float scl = __expf(m - mn);                                                \
    float el  = __expf(p - mn);                                                \
    den = fmaf(den, scl, el);                                                  \
    acc = fmaf(acc, scl, el * xlv);                                            \
    m = mn;                                                                    \
}

// ---------------- layer 2 fused GAT: wave/node, 4-way unroll -----------------
__global__ __launch_bounds__(256, 3) void k_gat2(
    const int* __restrict__ rs, const int* __restrict__ esrc,
    const float* __restrict__ ea_s, const float* __restrict__ We, const float* __restrict__ be,
    const float* __restrict__ att, const unsigned short* __restrict__ xl,
    const float* __restrict__ xr, const float* __restrict__ bias2, float* __restrict__ h2)
{
    int t = threadIdx.x, lane = t & 63, w = t >> 6;
    float Wreg[16];
#pragma unroll
    for (int k = 0; k < 16; ++k) Wreg[k] = We[k * HIDD + lane];
    float bev = be[lane], sav = att[lane], b2 = bias2[lane];
    for (int n = blockIdx.x * 4 + w; n < NN; n += gridDim.x * 4) {
        int beg = rs[n], end = rs[n + 1];
        float xrv = xr[(size_t)n * HIDD + lane];
        float m = -INFINITY, den = 0.f, acc = 0.f;
        int i = beg;
        for (; i + 4 <= end; i += 4) {
            int s0 = esrc[i], s1 = esrc[i + 1], s2 = esrc[i + 2], s3 = esrc[i + 3];
            unsigned short xu0 = xl[(size_t)s0 * HIDD + lane];
            unsigned short xu1 = xl[(size_t)s1 * HIDD + lane];
            unsigned short xu2 = xl[(size_t)s2 * HIDD + lane];
            unsigned short xu3 = xl[(size_t)s3 * HIDD + lane];
            const float* ep = ea_s + (size_t)i * EDD;
            float4 a00 = *((const float4*)(ep +  0));
            float4 a01 = *((const float4*)(ep +  4));
            float4 a02 = *((const float4*)(ep +  8));
            float4 a03 = *((const float4*)(ep + 12));
            float4 a10 = *((const float4*)(ep + 16));
            float4 a11 = *((const float4*)(ep + 20));
            float4 a12 = *((const float4*)(ep + 24));
            float4 a13 = *((const float4*)(ep + 28));
            float4 a20 = *((const float4*)(ep + 32));
            float4 a21 = *((const float4*)(ep + 36));
            float4 a22 = *((const float4*)(ep + 40));
            float4 a23 = *((const float4*)(ep + 44));
            float4 a30 = *((const float4*)(ep + 48));
            float4 a31 = *((const float4*)(ep + 52));
            float4 a32 = *((const float4*)(ep + 56));
            float4 a33 = *((const float4*)(ep + 60));
            GAT2_EDGE(xu0, a00, a01, a02, a03);
            GAT2_EDGE(xu1, a10, a11, a12, a13);
            GAT2_EDGE(xu2, a20, a21, a22, a23);
            GAT2_EDGE(xu3, a30, a31, a32, a33);
        }
        for (; i + 2 <= end; i += 2) {
            int s0 = esrc[i], s1 = esrc[i + 1];
            unsigned short xu0 = xl[(size_t)s0 * HIDD + lane];
            unsigned short xu1 = xl[(size_t)s1 * HIDD + lane];
            const float* ep = ea_s + (size_t)i * EDD;
            float4 a00 = *((const float4*)(ep +  0));
            float4 a01 = *((const float4*)(ep +  4));
            float4 a02 = *((const float4*)(ep +  8));
            float4 a03 = *((const float4*)(ep + 12));
            float4 a10 = *((const float4*)(ep + 16));
            float4 a11 = *((const float4*)(ep + 20));
            float4 a12 = *((const float4*)(ep + 24));
            float4 a13 = *((const float4*)(ep + 28));
            GAT2_EDGE(xu0, a00, a01, a02, a03);
            GAT2_EDGE(xu1, a10, a11, a12, a13);
        }
        if (i < end) {
            int s0 = esrc[i];
            unsigned short xu0 = xl[(size_t)s0 * HIDD + lane];
            const float* ep = ea_s + (size_t)i * EDD;
            float4 a00 = *((const float4*)(ep +  0));
            float4 a01 = *((const float4*)(ep +  4));
            float4 a02 = *((const float4*)(ep +  8));
            float4 a03 = *((const float4*)(ep + 12));
            GAT2_EDGE(xu0, a00, a01, a02, a03);
        }
        float r = den > 0.f ? 1.f / den : 0.f;
        float o = fmaf(acc, r, b2);
        h2[(size_t)n * HIDD + lane] = o > 0.f ? o : 0.f;
    }
}

// ---------------- edge-MLP node precompute: P/Q (bf16) = h2@Wm1[0:64 / 64:128]
__global__ __launch_bounds__(256) void k_pq(
    const float* __restrict__ h2, const float* __restrict__ Wm1,
    unsigned short* __restrict__ P, unsigned short* __restrict__ Q)
{
    __shared__ float As[16 * 68];
    int t = threadIdx.x;
    int row0 = blockIdx.x * 16;
    {
        int r = t >> 4, cc = (t & 15) * 4;
        float4 v = *((const float4*)(h2 + (size_t)(row0 + r) * HIDD + cc));
        *((float4*)&As[r * 68 + cc]) = v;
    }
    __syncthreads();
    int col = t & 63, g = t >> 6;
    float accP[4] = {0.f, 0.f, 0.f, 0.f}, accQ[4] = {0.f, 0.f, 0.f, 0.f};
    for (int k = 0; k < 64; k += 4) {
        float wp0 = Wm1[(k+0) * HIDD + col], wp1 = Wm1[(k+1) * HIDD + col];
        float wp2 = Wm1[(k+2) * HIDD + col], wp3 = Wm1[(k+3) * HIDD + col];
        float wq0 = Wm1[(64+k+0) * HIDD + col], wq1 = Wm1[(64+k+1) * HIDD + col];
        float wq2 = Wm1[(64+k+2) * HIDD + col], wq3 = Wm1[(64+k+3) * HIDD + col];
#pragma unroll
        for (int i = 0; i < 4; ++i) {
            float4 a = *((const float4*)&As[(g * 4 + i) * 68 + k]);
            accP[i] = fmaf(a.x, wp0, accP[i]); accP[i] = fmaf(a.y, wp1, accP[i]);
            accP[i] = fmaf(a.z, wp2, accP[i]); accP[i] = fmaf(a.w, wp3, accP[i]);
            accQ[i] = fmaf(a.x, wq0, accQ[i]); accQ[i] = fmaf(a.y, wq1, accQ[i]);
            accQ[i] = fmaf(a.z, wq2, accQ[i]); accQ[i] = fmaf(a.w, wq3, accQ[i]);
        }
    }
#pragma unroll
    for (int i = 0; i < 4; ++i) {
        int r = row0 + g * 4 + i;
        P[(size_t)r * HIDD + col] = f2bf(accP[i]);
        Q[(size_t)r * HIDD + col] = f2bf(accQ[i]);
    }
}

// ---------------- edge MLP: persistent, barrier-free, bf16 P/Q gathers -------
__global__ __launch_bounds__(256, 3) void k_edge(
    const int* __restrict__ src, const int* __restrict__ dst,
    const unsigned short* __restrict__ P, const unsigned short* __restrict__ Q,
    const float* __restrict__ ea,
    const float* __restrict__ Wm1, const float* __restrict__ bm1,
    const float* __restrict__ Wm2, const float* __restrict__ bm2,
    float* __restrict__ out)
{
    int t = threadIdx.x, lane = t & 63, w = t >> 6;
    int sub = lane & 15, grp = lane >> 4;
    int c4 = sub * 4;
    float4 Wreg[16];                   // Wm1 rows 128..143, cols c4..c4+3
#pragma unroll
    for (int k = 0; k < 16; ++k) Wreg[k] = *((const float4*)(Wm1 + (size_t)(128 + k) * HIDD + c4));
    float4 b1 = *((const float4*)(bm1 + c4));
    float w200 = Wm2[(c4+0)*2], w201 = Wm2[(c4+0)*2+1];
    float w210 = Wm2[(c4+1)*2], w211 = Wm2[(c4+1)*2+1];
    float w220 = Wm2[(c4+2)*2], w221 = Wm2[(c4+2)*2+1];
    float w230 = Wm2[(c4+3)*2], w231 = Wm2[(c4+3)*2+1];
    float b20 = bm2[0], b21 = bm2[1];
    for (int base = blockIdx.x * 16 + w * 4; base < EE; base += gridDim.x * 16) {
        int e = base + grp;
        int s = src[e], d = dst[e];
        ushort4 pu = *((const ushort4*)(P + (size_t)s * HIDD + c4));
        ushort4 qu = *((const ushort4*)(Q + (size_t)d * HIDD + c4));
        float4 ea0 = *((const float4*)(ea + (size_t)e * EDD));
        float4 ea1 = *((const float4*)(ea + (size_t)e * EDD + 4));
        float4 ea2 = *((const float4*)(ea + (size_t)e * EDD + 8));
        float4 ea3 = *((const float4*)(ea + (size_t)e * EDD + 12));
        float ev[16] = {ea0.x, ea0.y, ea0.z, ea0.w, ea1.x, ea1.y, ea1.z, ea1.w,
                        ea2.x, ea2.y, ea2.z, ea2.w, ea3.x, ea3.y, ea3.z, ea3.w};
        float4 hsum = b1;
#pragma unroll
        for (int k = 0; k < 16; ++k) {
            hsum.x = fmaf(ev[k], Wreg[k].x, hsum.x);
            hsum.y = fmaf(ev[k], Wreg[k].y, hsum.y);
            hsum.z = fmaf(ev[k], Wreg[k].z, hsum.z);
            hsum.w = fmaf(ev[k], Wreg[k].w, hsum.w);
        }
        float hx = fmaxf(hsum.x + bf2f(pu.x) + bf2f(qu.x), 0.f);
        float hy = fmaxf(hsum.y + bf2f(pu.y) + bf2f(qu.y), 0.f);
        float hz = fmaxf(hsum.z + bf2f(pu.z) + bf2f(qu.z), 0.f);
        float hw = fmaxf(hsum.w + bf2f(pu.w) + bf2f(qu.w), 0.f);
        float p0 = hx * w200 + hy * w210 + hz * w220 + hw * w230;
        float p1 = hx * w201 + hy * w211 + hz * w221 + hw * w231;
        p0 += __shfl_xor(p0, 1, 64);
        p0 += __shfl_xor(p0, 2, 64);
        p0 += __shfl_xor(p0, 4, 64);
        p0 += __shfl_xor(p0, 8, 64);
        p1 += __shfl_xor(p1, 1, 64);
        p1 += __shfl_xor(p1, 2, 64);
        p1 += __shfl_xor(p1, 4, 64);
        p1 += __shfl_xor(p1, 8, 64);
        if (sub == 0) ((float2*)out)[e] = make_float2(p0 + b20, p1 + b21);
    }
}

extern "C" void kernel_launch(void* const* d_in, const int* in_sizes, int n_in,
                              void* d_out, int out_size, void* d_ws, size_t ws_size,
                              hipStream_t stream)
{
    const float* x    = (const float*)d_in[0];
    const int*   ei   = (const int*)d_in[1];
    const float* ea   = (const float*)d_in[2];
    const float* W1l  = (const float*)d_in[3];
    const float* b1l  = (const float*)d_in[4];
    const float* W1r  = (const float*)d_in[5];
    const float* b1r  = (const float*)d_in[6];
    const float* W1e  = (const float*)d_in[7];
    const float* b1e  = (const float*)d_in[8];
    const float* att1 = (const float*)d_in[9];
    const float* bias1= (const float*)d_in[10];
    const float* W2l  = (const float*)d_in[11];
    const float* b2l  = (const float*)d_in[12];
    const float* W2r  = (const float*)d_in[13];
    const float* b2r  = (const float*)d_in[14];
    const float* W2e  = (const float*)d_in[15];
    const float* b2e  = (const float*)d_in[16];
    const float* att2 = (const float*)d_in[17];
    const float* bias2= (const float*)d_in[18];
    const float* Wm1  = (const float*)d_in[19];
    const float* bm1  = (const float*)d_in[20];
    const float* Wm2  = (const float*)d_in[21];
    const float* bm2  = (const float*)d_in[22];
    float* out = (float*)d_out;
    const int* srcp = ei;
    const int* dstp = ei + EE;

    float* ws = (float*)d_ws;
    const size_t NC1  = (size_t)NN * C1;     // 12.8M elements
    const size_t NH64 = (size_t)NN * HIDD;   // 3.2M elements
    // Lifetime-aliased layout (float units):
    size_t o_xl1u = 0;                       // ushort[NN*C1] -> 6.4M floats
    size_t o_xr1  = o_xl1u + NC1 / 2;        // 12.8M, ends 19.2M
    // Reuse of R1 after gat1:
    size_t o_xl2u = 0;                       // ushort[NN*HIDD] -> 1.6M
    size_t o_xr2  = o_xl2u + NH64 / 2;       // 3.2M, ends 4.8M
    size_t o_h2   = o_xr2 + NH64;            // 3.2M, ends 8.0M
    size_t o_Pu   = o_h2 + NH64;             // 1.6M
    size_t o_Qu   = o_Pu + NH64 / 2;         // 1.6M, ends 11.2M  (< 19.2M OK)
    // Persistent:
    size_t o_h1   = o_xr1 + NC1;             // 19.2M .. 32.0M
    size_t o_ea_s = o_h1 + NC1;              // 32.0M .. 41.6M
    size_t o_cnt  = o_ea_s + (size_t)EE * EDD;
    size_t o_rs   = o_cnt + 2 * (size_t)NN;
    size_t o_esrc = o_rs + (size_t)NN + 8;

    unsigned short* xl1u = (unsigned short*)(ws + o_xl1u);
    unsigned short* xl2u = (unsigned short*)(ws + o_xl2u);
    unsigned short* Pu   = (unsigned short*)(ws + o_Pu);
    unsigned short* Qu   = (unsigned short*)(ws + o_Qu);
    float* ea_s = ws + o_ea_s;
    int* cnt  = (int*)(ws + o_cnt);
    int* cur  = cnt + NN;
    int* rs   = (int*)(ws + o_rs);
    int* esrc = (int*)(ws + o_esrc);

    hipMemsetAsync(cnt, 0, 2 * (size_t)NN * sizeof(int), stream);

    dim3 blk(256);
    k_hist<<<1024, blk, 0, stream>>>(dstp, cnt);
    k_scan<<<1, 1024, 0, stream>>>(cnt, rs);
    k_scatter<<<1024, blk, 0, stream>>>(srcp, dstp, ea, rs, cur, esrc, ea_s);

    k_lin1<<<3125, blk, 0, stream>>>(x, W1l, b1l, W1r, b1r, xl1u, ws + o_xr1);
    k_gat1<<<2048, blk, 0, stream>>>(rs, esrc, ea_s, W1e, b1e, att1,
                                     xl1u, ws + o_xr1, ws + o_h1);
    k_lin2<<<3125, blk, 0, stream>>>(ws + o_h1, bias1, W2l, b2l, W2r, b2r,
                                     xl2u, ws + o_xr2);
    k_gat2<<<2048, blk, 0, stream>>>(rs, esrc, ea_s, W2e, b2e, att2,
                                     xl2u, ws + o_xr2, bias2, ws + o_h2);
    k_pq<<<3125, blk, 0, stream>>>(ws + o_h2, Wm1, Pu, Qu);
    k_edge<<<2048, blk, 0, stream>>>(srcp, dstp, Pu, Qu, ea,
                                     Wm1, bm1, Wm2, bm2, out);
}

// Round 12
// 654.127 us; speedup vs baseline: 1.4132x; 1.4132x over previous
//
#include <hip/hip_runtime.h>
#include <math.h>

#define NN 50000
#define EE 600000
#define IND 128
#define HIDD 64
#define NH 4
#define EDD 16
#define OUTD 2
#define C1 256  /* NH*HID */

__device__ __forceinline__ float lrelu(float v){ return v > 0.f ? v : 0.2f*v; }
// bf16 pack (round-to-nearest-even) / unpack
__device__ __forceinline__ unsigned short f2bf(float f){
    unsigned b = __float_as_uint(f);
    b += 0x7FFF + ((b >> 16) & 1);
    return (unsigned short)(b >> 16);
}
__device__ __forceinline__ float bf2f(unsigned short h){
    return __uint_as_float(((unsigned)h) << 16);
}

// ---------------- CSR build: histogram ---------------------------------------
__global__ __launch_bounds__(256) void k_hist(const int* __restrict__ dst, int* __restrict__ cnt)
{
    int stride = gridDim.x * blockDim.x;
    for (int e = blockIdx.x * blockDim.x + threadIdx.x; e < EE; e += stride)
        atomicAdd(&cnt[dst[e]], 1);
}

// ---------------- CSR build: exclusive scan (single block, 1024 thr) ---------
__global__ __launch_bounds__(1024) void k_scan(const int* __restrict__ cnt, int* __restrict__ rs)
{
    __shared__ int wsum[16];
    __shared__ int wpref[16];
    int t = threadIdx.x, lane = t & 63, w = t >> 6;
    int running = 0;
    for (int base = 0; base < NN; base += 1024) {
        int idx = base + t;
        int v = (idx < NN) ? cnt[idx] : 0;
        int sc = v;
#pragma unroll
        for (int off = 1; off < 64; off <<= 1) {
            int u = __shfl_up(sc, off, 64);
            if (lane >= off) sc += u;
        }
        if (lane == 63) wsum[w] = sc;
        __syncthreads();
        if (w == 0 && lane < 16) {
            int x = wsum[lane];
#pragma unroll
            for (int off = 1; off < 16; off <<= 1) {
                int u = __shfl_up(x, off, 64);
                if (lane >= off) x += u;
            }
            wpref[lane] = x;
        }
        __syncthreads();
        int woff = (w == 0) ? 0 : wpref[w - 1];
        if (idx < NN) rs[idx] = running + woff + sc - v;
        running += wpref[15];
        __syncthreads();
    }
    if (t == 0) rs[NN] = running;
}

// ---------------- CSR build: scatter src ids + edge attrs in CSR order -------
__global__ __launch_bounds__(256) void k_scatter(
    const int* __restrict__ src, const int* __restrict__ dst,
    const float* __restrict__ ea,
    const int* __restrict__ rs, int* __restrict__ cur,
    int* __restrict__ esrc, float* __restrict__ ea_s)
{
    int stride = gridDim.x * blockDim.x;
    for (int e = blockIdx.x * blockDim.x + threadIdx.x; e < EE; e += stride) {
        int d = dst[e];
        int p = rs[d] + atomicAdd(&cur[d], 1);
        esrc[p] = src[e];
        const float4* s4 = (const float4*)(ea + (size_t)e * EDD);
        float4* d4 = (float4*)(ea_s + (size_t)p * EDD);
        d4[0] = s4[0]; d4[1] = s4[1]; d4[2] = s4[2]; d4[3] = s4[3];
    }
}

// ---------------- layer 1 node linear: xl1(bf16) = x@W1l+b1l, xr1 = x@W1r+b1r
__global__ __launch_bounds__(256) void k_lin1(
    const float* __restrict__ x, const float* __restrict__ Wl, const float* __restrict__ bl,
    const float* __restrict__ Wr, const float* __restrict__ br,
    unsigned short* __restrict__ xl, float* __restrict__ xr)
{
    __shared__ float As[16 * IND];
    int t = threadIdx.x;
    int row0 = blockIdx.x * 16;
#pragma unroll
    for (int j = 0; j < 8; ++j) {
        int idx = t + j * 256;
        int r = idx >> 7, c = idx & 127;
        As[idx] = (row0 + r < NN) ? x[(size_t)(row0 + r) * IND + c] : 0.f;
    }
    __syncthreads();
    float accl[16], accr[16];
    float bL = bl[t], bR = br[t];
#pragma unroll
    for (int i = 0; i < 16; ++i) { accl[i] = bL; accr[i] = bR; }
    for (int k = 0; k < IND; k += 4) {
        float wl0 = Wl[(k+0) * C1 + t], wl1 = Wl[(k+1) * C1 + t];
        float wl2 = Wl[(k+2) * C1 + t], wl3 = Wl[(k+3) * C1 + t];
        float wr0 = Wr[(k+0) * C1 + t], wr1 = Wr[(k+1) * C1 + t];
        float wr2 = Wr[(k+2) * C1 + t], wr3 = Wr[(k+3) * C1 + t];
#pragma unroll
        for (int i = 0; i < 16; ++i) {
            float4 a = *((const float4*)&As[i * IND + k]);
            accl[i] = fmaf(a.x, wl0, accl[i]); accl[i] = fmaf(a.y, wl1, accl[i]);
            accl[i] = fmaf(a.z, wl2, accl[i]); accl[i] = fmaf(a.w, wl3, accl[i]);
            accr[i] = fmaf(a.x, wr0, accr[i]); accr[i] = fmaf(a.y, wr1, accr[i]);
            accr[i] = fmaf(a.z, wr2, accr[i]); accr[i] = fmaf(a.w, wr3, accr[i]);
        }
    }
#pragma unroll
    for (int i = 0; i < 16; ++i) {
        int r = row0 + i;
        if (r < NN) {
            xl[(size_t)r * C1 + t] = f2bf(accl[i]);
            xr[(size_t)r * C1 + t] = accr[i];
        }
    }
}

// one online-softmax edge step for layer 1 (uses outer-scope Wreg/sb4/sa4/xr4/m/den/acc)
#define GAT1_EDGE(XU, A0, A1, A2, A3) {                                        \
    float4 xl4 = make_float4(bf2f((XU).x), bf2f((XU).y), bf2f((XU).z), bf2f((XU).w)); \
    float ev[16] = {(A0).x,(A0).y,(A0).z,(A0).w,(A1).x,(A1).y,(A1).z,(A1).w,   \
                    (A2).x,(A2).y,(A2).z,(A2).w,(A3).x,(A3).y,(A3).z,(A3).w};  \
    float4 xe = sb4;                                                           \
    _Pragma("unroll")                                                          \
    for (int k = 0; k < 16; ++k) {                                             \
        xe.x = fmaf(ev[k], Wreg[k].x, xe.x);                                   \
        xe.y = fmaf(ev[k], Wreg[k].y, xe.y);                                   \
        xe.z = fmaf(ev[k], Wreg[k].z, xe.z);                                   \
        xe.w = fmaf(ev[k], Wreg[k].w, xe.w);                                   \
    }                                                                          \
    float vx = lrelu(xl4.x + xr4.x + xe.x);                                    \
    float vy = lrelu(xl4.y + xr4.y + xe.y);                                    \
    float vz = lrelu(xl4.z + xr4.z + xe.z);                                    \
    float vw = lrelu(xl4.w + xr4.w + xe.w);                                    \
    float p = vx * sa4.x + vy * sa4.y + vz * sa4.z + vw * sa4.w;               \
    p += __shfl_xor(p, 1, 64);                                                 \
    p += __shfl_xor(p, 2, 64);                                                 \
    p += __shfl_xor(p, 4, 64);                                                 \
    p += __shfl_xor(p, 8, 64);                                                 \
    float mn = fmaxf(m, p);                                                    \
    float scl = __expf(m - mn);                                                \
    float el  = __expf(p - mn);                                                \
    den = fmaf(den, scl, el);                                                  \
    acc.x = fmaf(acc.x, scl, el * xl4.x);                                      \
    acc.y = fmaf(acc.y, scl, el * xl4.y);                                      \
    acc.z = fmaf(acc.z, scl, el * xl4.z);                                      \
    acc.w = fmaf(acc.w, scl, el * xl4.w);                                      \
    m = mn;                                                                    \
}

// ---------------- layer 1 fused GAT: wave/node, 2-way unroll (R10 best) ------
// beg/end readfirstlane'd -> compiler can prove i, esrc[i], ea_s addresses
// wave-uniform and move them to the scalar pipe (s_load), leaving only the
// xl gather on the vector-VMEM path.
__global__ __launch_bounds__(256, 3) void k_gat1(
    const int* __restrict__ rs, const int* __restrict__ esrc,
    const float* __restrict__ ea_s, const float* __restrict__ We, const float* __restrict__ be,
    const float* __restrict__ att, const unsigned short* __restrict__ xl,
    const float* __restrict__ xr, float* __restrict__ h1)
{
    int t = threadIdx.x, lane = t & 63, w = t >> 6;
    int c4 = lane * 4;                 // lane owns 4 contiguous channels, head = lane>>4
    float4 Wreg[16];
#pragma unroll
    for (int k = 0; k < 16; ++k) Wreg[k] = *((const float4*)(We + k * C1 + c4));
    float4 sb4 = *((const float4*)(be + c4));
    float4 sa4 = *((const float4*)(att + c4));
    for (int n = blockIdx.x * 4 + w; n < NN; n += gridDim.x * 4) {
        int beg = __builtin_amdgcn_readfirstlane(rs[n]);
        int end = __builtin_amdgcn_readfirstlane(rs[n + 1]);
        float4 xr4 = *((const float4*)(xr + (size_t)n * C1 + c4));
        float m = -INFINITY, den = 0.f;
        float4 acc = make_float4(0.f, 0.f, 0.f, 0.f);
        int i = beg;
        for (; i + 2 <= end; i += 2) {
            int s0 = esrc[i], s1 = esrc[i + 1];
            ushort4 xu0 = *((const ushort4*)(xl + (size_t)s0 * C1 + c4));
            ushort4 xu1 = *((const ushort4*)(xl + (size_t)s1 * C1 + c4));
            const float* ep = ea_s + (size_t)i * EDD;
            float4 a00 = *((const float4*)(ep +  0));
            float4 a01 = *((const float4*)(ep +  4));
            float4 a02 = *((const float4*)(ep +  8));
            float4 a03 = *((const float4*)(ep + 12));
            float4 a10 = *((const float4*)(ep + 16));
            float4 a11 = *((const float4*)(ep + 20));
            float4 a12 = *((const float4*)(ep + 24));
            float4 a13 = *((const float4*)(ep + 28));
            GAT1_EDGE(xu0, a00, a01, a02, a03);
            GAT1_EDGE(xu1, a10, a11, a12, a13);
        }
        if (i < end) {
            int s0 = esrc[i];
            ushort4 xu0 = *((const ushort4*)(xl + (size_t)s0 * C1 + c4));
            const float* ep = ea_s + (size_t)i * EDD;
            float4 a00 = *((const float4*)(ep +  0));
            float4 a01 = *((const float4*)(ep +  4));
            float4 a02 = *((const float4*)(ep +  8));
            float4 a03 = *((const float4*)(ep + 12));
            GAT1_EDGE(xu0, a00, a01, a02, a03);
        }
        float r = den > 0.f ? 1.f / den : 0.f;
        float4 o = make_float4(acc.x * r, acc.y * r, acc.z * r, acc.w * r);
        *((float4*)(h1 + (size_t)n * C1 + c4)) = o;
    }
}

// ---------------- layer 2 node linear (fuses bias1+relu on load) -------------
__global__ __launch_bounds__(256) void k_lin2(
    const float* __restrict__ h1acc, const float* __restrict__ bias1,
    const float* __restrict__ Wl, const float* __restrict__ bl,
    const float* __restrict__ Wr, const float* __restrict__ br,
    unsigned short* __restrict__ xl2, float* __restrict__ xr2)
{
    __shared__ float As[16 * 260];
    int t = threadIdx.x;
    int row0 = blockIdx.x * 16;
    float b1 = bias1[t];
#pragma unroll
    for (int j = 0; j < 16; ++j) {
        float v = (row0 + j < NN) ? h1acc[(size_t)(row0 + j) * C1 + t] : 0.f;
        v = v + b1;
        As[j * 260 + t] = v > 0.f ? v : 0.f;
    }
    __syncthreads();
    int col = t & 63, g = t >> 6;
    float accl[4], accr[4];
    float bL = bl[col], bR = br[col];
#pragma unroll
    for (int i = 0; i < 4; ++i) { accl[i] = bL; accr[i] = bR; }
    for (int k = 0; k < C1; k += 4) {
        float wl0 = Wl[(k+0) * HIDD + col], wl1 = Wl[(k+1) * HIDD + col];
        float wl2 = Wl[(k+2) * HIDD + col], wl3 = Wl[(k+3) * HIDD + col];
        float wr0 = Wr[(k+0) * HIDD + col], wr1 = Wr[(k+1) * HIDD + col];
        float wr2 = Wr[(k+2) * HIDD + col], wr3 = Wr[(k+3) * HIDD + col];
#pragma unroll
        for (int i = 0; i < 4; ++i) {
            float4 a = *((const float4*)&As[(g * 4 + i) * 260 + k]);
            accl[i] = fmaf(a.x, wl0, accl[i]); accl[i] = fmaf(a.y, wl1, accl[i]);
            accl[i] = fmaf(a.z, wl2, accl[i]); accl[i] = fmaf(a.w, wl3, accl[i]);
            accr[i] = fmaf(a.x, wr0, accr[i]); accr[i] = fmaf(a.y, wr1, accr[i]);
            accr[i] = fmaf(a.z, wr2, accr[i]); accr[i] = fmaf(a.w, wr3, accr[i]);
        }
    }
#pragma unroll
    for (int i = 0; i < 4; ++i) {
        int r = row0 + g * 4 + i;
        if (r < NN) {
            xl2[(size_t)r * HIDD + col] = f2bf(accl[i]);
            xr2[(size_t)r * HIDD + col] = accr[i];
        }
    }
}

// one online-softmax edge step for layer 2
#define GAT2_EDGE(XU, A0, A1, A2, A3) {                                        \
    float xlv = bf2f(XU);                                                      \
    float ev[16] = {(A0).x,(A0).y,(A0).z,(A0).w,(A1).x,(A1).y,(A1).z,(A1).w,   \
                    (A2).x,(A2).y,(A2).z,(A2).w,(A3).x,(A3).y,(A3).z,(A3).w};  \
    float xe = bev;                                                            \
    _Pragma("unroll")                                                          \
    for (int k = 0; k < 16; ++k) xe = fmaf(ev[k], Wreg[k], xe);                \
    float v = lrelu(xlv + xrv + xe);                                           \
    float p = v * sav;                                                         \
    p += __shfl_xor(p, 1, 64);                                                 \
    p += __shfl_xor(p, 2, 64);                                                 \
    p += __shfl_xor(p, 4, 64);                                                 \
    p += __shfl_xor(p, 8, 64);                                                 \
    p += __shfl_xor(p, 16, 64);                                                \
    p += __shfl_xor(p, 32, 64);                                                \
    float mn = fmaxf(m, p);                                                    \
    float scl = __expf(m - mn);                                                \
    float el  = __expf(p - mn);                                                \
    den = fmaf(den, scl, el);                                                  \
    acc = fmaf(acc, scl, el * xlv);                                            \
    m = mn;                                                                    \
}

// ---------------- layer 2 fused GAT: wave/node, 2-way unroll -----------------
__global__ __launch_bounds__(256) void k_gat2(
    const int* __restrict__ rs, const int* __restrict__ esrc,
    const float* __restrict__ ea_s, const float* __restrict__ We, const float* __restrict__ be,
    const float* __restrict__ att, const unsigned short* __restrict__ xl,
    const float* __restrict__ xr, const float* __restrict__ bias2, float* __restrict__ h2)
{
    int t = threadIdx.x, lane = t & 63, w = t >> 6;
    float Wreg[16];
#pragma unroll
    for (int k = 0; k < 16; ++k) Wreg[k] = We[k * HIDD + lane];
    float bev = be[lane], sav = att[lane], b2 = bias2[lane];
    for (int n = blockIdx.x * 4 + w; n < NN; n += gridDim.x * 4) {
        int beg = __builtin_amdgcn_readfirstlane(rs[n]);
        int end = __builtin_amdgcn_readfirstlane(rs[n + 1]);
        float xrv = xr[(size_t)n * HIDD + lane];
        float m = -INFINITY, den = 0.f, acc = 0.f;
        int i = beg;
        for (; i + 2 <= end; i += 2) {
            int s0 = esrc[i], s1 = esrc[i + 1];
            unsigned short xu0 = xl[(size_t)s0 * HIDD + lane];
            unsigned short xu1 = xl[(size_t)s1 * HIDD + lane];
            const float* ep = ea_s + (size_t)i * EDD;
            float4 a00 = *((const float4*)(ep +  0));
            float4 a01 = *((const float4*)(ep +  4));
            float4 a02 = *((const float4*)(ep +  8));
            float4 a03 = *((const float4*)(ep + 12));
            float4 a10 = *((const float4*)(ep + 16));
            float4 a11 = *((const float4*)(ep + 20));
            float4 a12 = *((const float4*)(ep + 24));
            float4 a13 = *((const float4*)(ep + 28));
            GAT2_EDGE(xu0, a00, a01, a02, a03);
            GAT2_EDGE(xu1, a10, a11, a12, a13);
        }
        if (i < end) {
            int s0 = esrc[i];
            unsigned short xu0 = xl[(size_t)s0 * HIDD + lane];
            const float* ep = ea_s + (size_t)i * EDD;
            float4 a00 = *((const float4*)(ep +  0));
            float4 a01 = *((const float4*)(ep +  4));
            float4 a02 = *((const float4*)(ep +  8));
            float4 a03 = *((const float4*)(ep + 12));
            GAT2_EDGE(xu0, a00, a01, a02, a03);
        }
        float r = den > 0.f ? 1.f / den : 0.f;
        float o = fmaf(acc, r, b2);
        h2[(size_t)n * HIDD + lane] = o > 0.f ? o : 0.f;
    }
}

// ---------------- edge-MLP node precompute: P/Q (bf16) = h2@Wm1[0:64 / 64:128]
__global__ __launch_bounds__(256) void k_pq(
    const float* __restrict__ h2, const float* __restrict__ Wm1,
    unsigned short* __restrict__ P, unsigned short* __restrict__ Q)
{
    __shared__ float As[16 * 68];
    int t = threadIdx.x;
    int row0 = blockIdx.x * 16;
    {
        int r = t >> 4, cc = (t & 15) * 4;
        float4 v = *((const float4*)(h2 + (size_t)(row0 + r) * HIDD + cc));
        *((float4*)&As[r * 68 + cc]) = v;
    }
    __syncthreads();
    int col = t & 63, g = t >> 6;
    float accP[4] = {0.f, 0.f, 0.f, 0.f}, accQ[4] = {0.f, 0.f, 0.f, 0.f};
    for (int k = 0; k < 64; k += 4) {
        float wp0 = Wm1[(k+0) * HIDD + col], wp1 = Wm1[(k+1) * HIDD + col];
        float wp2 = Wm1[(k+2) * HIDD + col], wp3 = Wm1[(k+3) * HIDD + col];
        float wq0 = Wm1[(64+k+0) * HIDD + col], wq1 = Wm1[(64+k+1) * HIDD + col];
        float wq2 = Wm1[(64+k+2) * HIDD + col], wq3 = Wm1[(64+k+3) * HIDD + col];
#pragma unroll
        for (int i = 0; i < 4; ++i) {
            float4 a = *((const float4*)&As[(g * 4 + i) * 68 + k]);
            accP[i] = fmaf(a.x, wp0, accP[i]); accP[i] = fmaf(a.y, wp1, accP[i]);
            accP[i] = fmaf(a.z, wp2, accP[i]); accP[i] = fmaf(a.w, wp3, accP[i]);
            accQ[i] = fmaf(a.x, wq0, accQ[i]); accQ[i] = fmaf(a.y, wq1, accQ[i]);
            accQ[i] = fmaf(a.z, wq2, accQ[i]); accQ[i] = fmaf(a.w, wq3, accQ[i]);
        }
    }
#pragma unroll
    for (int i = 0; i < 4; ++i) {
        int r = row0 + g * 4 + i;
        P[(size_t)r * HIDD + col] = f2bf(accP[i]);
        Q[(size_t)r * HIDD + col] = f2bf(accQ[i]);
    }
}

// ---------------- edge MLP: persistent, barrier-free, bf16 P/Q gathers -------
__global__ __launch_bounds__(256, 3) void k_edge(
    const int* __restrict__ src, const int* __restrict__ dst,
    const unsigned short* __restrict__ P, const unsigned short* __restrict__ Q,
    const float* __restrict__ ea,
    const float* __restrict__ Wm1, const float* __restrict__ bm1,
    const float* __restrict__ Wm2, const float* __restrict__ bm2,
    float* __restrict__ out)
{
    int t = threadIdx.x, lane = t & 63, w = t >> 6;
    int sub = lane & 15, grp = lane >> 4;
    int c4 = sub * 4;
    float4 Wreg[16];                   // Wm1 rows 128..143, cols c4..c4+3
#pragma unroll
    for (int k = 0; k < 16; ++k) Wreg[k] = *((const float4*)(Wm1 + (size_t)(128 + k) * HIDD + c4));
    float4 b1 = *((const float4*)(bm1 + c4));
    float w200 = Wm2[(c4+0)*2], w201 = Wm2[(c4+0)*2+1];
    float w210 = Wm2[(c4+1)*2], w211 = Wm2[(c4+1)*2+1];
    float w220 = Wm2[(c4+2)*2], w221 = Wm2[(c4+2)*2+1];
    float w230 = Wm2[(c4+3)*2], w231 = Wm2[(c4+3)*2+1];
    float b20 = bm2[0], b21 = bm2[1];
    for (int base = blockIdx.x * 16 + w * 4; base < EE; base += gridDim.x * 16) {
        int e = base + grp;
        int s = src[e], d = dst[e];
        ushort4 pu = *((const ushort4*)(P + (size_t)s * HIDD + c4));
        ushort4 qu = *((const ushort4*)(Q + (size_t)d * HIDD + c4));
        float4 ea0 = *((const float4*)(ea + (size_t)e * EDD));
        float4 ea1 = *((const float4*)(ea + (size_t)e * EDD + 4));
        float4 ea2 = *((const float4*)(ea + (size_t)e * EDD + 8));
        float4 ea3 = *((const float4*)(ea + (size_t)e * EDD + 12));
        float ev[16] = {ea0.x, ea0.y, ea0.z, ea0.w, ea1.x, ea1.y, ea1.z, ea1.w,
                        ea2.x, ea2.y, ea2.z, ea2.w, ea3.x, ea3.y, ea3.z, ea3.w};
        float4 hsum = b1;
#pragma unroll
        for (int k = 0; k < 16; ++k) {
            hsum.x = fmaf(ev[k], Wreg[k].x, hsum.x);
            hsum.y = fmaf(ev[k], Wreg[k].y, hsum.y);
            hsum.z = fmaf(ev[k], Wreg[k].z, hsum.z);
            hsum.w = fmaf(ev[k], Wreg[k].w, hsum.w);
        }
        float hx = fmaxf(hsum.x + bf2f(pu.x) + bf2f(qu.x), 0.f);
        float hy = fmaxf(hsum.y + bf2f(pu.y) + bf2f(qu.y), 0.f);
        float hz = fmaxf(hsum.z + bf2f(pu.z) + bf2f(qu.z), 0.f);
        float hw = fmaxf(hsum.w + bf2f(pu.w) + bf2f(qu.w), 0.f);
        float p0 = hx * w200 + hy * w210 + hz * w220 + hw * w230;
        float p1 = hx * w201 + hy * w211 + hz * w221 + hw * w231;
        p0 += __shfl_xor(p0, 1, 64);
        p0 += __shfl_xor(p0, 2, 64);
        p0 += __shfl_xor(p0, 4, 64);
        p0 += __shfl_xor(p0, 8, 64);
        p1 += __shfl_xor(p1, 1, 64);
        p1 += __shfl_xor(p1, 2, 64);
        p1 += __shfl_xor(p1, 4, 64);
        p1 += __shfl_xor(p1, 8, 64);
        if (sub == 0) ((float2*)out)[e] = make_float2(p0 + b20, p1 + b21);
    }
}

extern "C" void kernel_launch(void* const* d_in, const int* in_sizes, int n_in,
                              void* d_out, int out_size, void* d_ws, size_t ws_size,
                              hipStream_t stream)
{
    const float* x    = (const float*)d_in[0];
    const int*   ei   = (const int*)d_in[1];
    const float* ea   = (const float*)d_in[2];
    const float* W1l  = (const float*)d_in[3];
    const float* b1l  = (const float*)d_in[4];
    const float* W1r  = (const float*)d_in[5];
    const float* b1r  = (const float*)d_in[6];
    const float* W1e  = (const float*)d_in[7];
    const float* b1e  = (const float*)d_in[8];
    const float* att1 = (const float*)d_in[9];
    const float* bias1= (const float*)d_in[10];
    const float* W2l  = (const float*)d_in[11];
    const float* b2l  = (const float*)d_in[12];
    const float* W2r  = (const float*)d_in[13];
    const float* b2r  = (const float*)d_in[14];
    const float* W2e  = (const float*)d_in[15];
    const float* b2e  = (const float*)d_in[16];
    const float* att2 = (const float*)d_in[17];
    const float* bias2= (const float*)d_in[18];
    const float* Wm1  = (const float*)d_in[19];
    const float* bm1  = (const float*)d_in[20];
    const float* Wm2  = (const float*)d_in[21];
    const float* bm2  = (const float*)d_in[22];
    float* out = (float*)d_out;
    const int* srcp = ei;
    const int* dstp = ei + EE;

    float* ws = (float*)d_ws;
    const size_t NC1  = (size_t)NN * C1;     // 12.8M elements
    const size_t NH64 = (size_t)NN * HIDD;   // 3.2M elements
    // Lifetime-aliased layout (float units):
    size_t o_xl1u = 0;                       // ushort[NN*C1] -> 6.4M floats
    size_t o_xr1  = o_xl1u + NC1 / 2;        // 12.8M, ends 19.2M
    // Reuse of R1 after gat1:
    size_t o_xl2u = 0;                       // ushort[NN*HIDD] -> 1.6M
    size_t o_xr2  = o_xl2u + NH64 / 2;       // 3.2M, ends 4.8M
    size_t o_h2   = o_xr2 + NH64;            // 3.2M, ends 8.0M
    size_t o_Pu   = o_h2 + NH64;             // 1.6M
    size_t o_Qu   = o_Pu + NH64 / 2;         // 1.6M, ends 11.2M  (< 19.2M OK)
    // Persistent:
    size_t o_h1   = o_xr1 + NC1;             // 19.2M .. 32.0M
    size_t o_ea_s = o_h1 + NC1;              // 32.0M .. 41.6M
    size_t o_cnt  = o_ea_s + (size_t)EE * EDD;
    size_t o_rs   = o_cnt + 2 * (size_t)NN;
    size_t o_esrc = o_rs + (size_t)NN + 8;

    unsigned short* xl1u = (unsigned short*)(ws + o_xl1u);
    unsigned short* xl2u = (unsigned short*)(ws + o_xl2u);
    unsigned short* Pu   = (unsigned short*)(ws + o_Pu);
    unsigned short* Qu   = (unsigned short*)(ws + o_Qu);
    float* ea_s = ws + o_ea_s;
    int* cnt  = (int*)(ws + o_cnt);
    int* cur  = cnt + NN;
    int* rs   = (int*)(ws + o_rs);
    int* esrc = (int*)(ws + o_esrc);

    hipMemsetAsync(cnt, 0, 2 * (size_t)NN * sizeof(int), stream);

    dim3 blk(256);
    k_hist<<<1024, blk, 0, stream>>>(dstp, cnt);
    k_scan<<<1, 1024, 0, stream>>>(cnt, rs);
    k_scatter<<<1024, blk, 0, stream>>>(srcp, dstp, ea, rs, cur, esrc, ea_s);

    k_lin1<<<3125, blk, 0, stream>>>(x, W1l, b1l, W1r, b1r, xl1u, ws + o_xr1);
    k_gat1<<<2048, blk, 0, stream>>>(rs, esrc, ea_s, W1e, b1e, att1,
                                     xl1u, ws + o_xr1, ws + o_h1);
    k_lin2<<<3125, blk, 0, stream>>>(ws + o_h1, bias1, W2l, b2l, W2r, b2r,
                                     xl2u, ws + o_xr2);
    k_gat2<<<2048, blk, 0, stream>>>(rs, esrc, ea_s, W2e, b2e, att2,
                                     xl2u, ws + o_xr2, bias2, ws + o_h2);
    k_pq<<<3125, blk, 0, stream>>>(ws + o_h2, Wm1, Pu, Qu);
    k_edge<<<2048, blk, 0, stream>>>(srcp, dstp, Pu, Qu, ea,
                                     Wm1, bm1, Wm2, bm2, out);
}